// Round 1
// baseline (62.324 us; speedup 1.0000x reference)
//
#include <hip/hip_runtime.h>
#include <math.h>

#define B 16
#define N 4096
#define K 4096
#define OBJ_ELEMS (8*512*3)   // 12288 per batch
#define KSEG 16
#define KS (K/KSEG)           // 256 ori points per segment
#define BLK1 512
#define P 8                   // adv points per thread: 512*8 = 4096 = N
#define CD_W 0.2f
#define EPS_F 1e-7f

// ws layout (floats):
//   [0,           B*K*4)        packed ori {x,y,z,o2}
//   [PART_OFF,    +KSEG*B*N)    partial minima of (o2 - 2*dot)
//   [RES_OFF,     +2*B)         per-batch chamfer loss1 [B], l2 [B]
#define PACKED_SZ (B*K*4)
#define PART_OFF  PACKED_SZ
#define PART_SZ   (KSEG*B*N)
#define RES_OFF   (PART_OFF + PART_SZ)

__global__ __launch_bounds__(256) void pack_ori_kernel(
    const float* __restrict__ ori, float* __restrict__ packed)
{
    int i = blockIdx.x * 256 + threadIdx.x;   // point index in [0, B*K)
    if (i >= B * K) return;
    float x = ori[i*3 + 0];
    float y = ori[i*3 + 1];
    float z = ori[i*3 + 2];
    float4 v = make_float4(x, y, z, x*x + y*y + z*z);
    reinterpret_cast<float4*>(packed)[i] = v;
}

__global__ __launch_bounds__(BLK1) void chamfer_part_kernel(
    const float* __restrict__ adv, const float* __restrict__ packed,
    float* __restrict__ part)
{
    __shared__ float4 lo[KS];
    const int kseg = blockIdx.y;
    const int b    = blockIdx.z;
    const int tid  = threadIdx.x;

    // stage this block's ori segment into LDS (packed {x,y,z,o2})
    if (tid < KS) {
        lo[tid] = reinterpret_cast<const float4*>(packed)[b*K + kseg*KS + tid];
    }

    // load this thread's 8 adv points into registers
    float ax[P], ay[P], az[P], m[P];
    #pragma unroll
    for (int p = 0; p < P; ++p) {
        int n = tid + p * BLK1;
        ax[p] = adv[(b*N + n)*3 + 0];
        ay[p] = adv[(b*N + n)*3 + 1];
        az[p] = adv[(b*N + n)*3 + 2];
        m[p]  = INFINITY;
    }
    __syncthreads();

    #pragma unroll 4
    for (int k = 0; k < KS; ++k) {
        float4 o = lo[k];
        #pragma unroll
        for (int p = 0; p < P; ++p) {
            float dot = ax[p]*o.x + ay[p]*o.y + az[p]*o.z;   // 3 fma
            float v   = __builtin_fmaf(-2.0f, dot, o.w);     // o2 - 2*dot
            m[p] = fminf(m[p], v);
        }
    }

    #pragma unroll
    for (int p = 0; p < P; ++p) {
        int n = tid + p * BLK1;
        part[(kseg*B + b)*N + n] = m[p];
    }
}

__global__ __launch_bounds__(256) void batch_reduce_kernel(
    const float* __restrict__ adv, const float* __restrict__ part,
    const float* __restrict__ adv_obj, const float* __restrict__ ori_obj,
    float* __restrict__ res)
{
    const int b   = blockIdx.x;
    const int tid = threadIdx.x;

    // chamfer: sum over n of (a2[n] + min over segments)
    float csum = 0.f;
    for (int n = tid; n < N; n += 256) {
        float x = adv[(b*N + n)*3 + 0];
        float y = adv[(b*N + n)*3 + 1];
        float z = adv[(b*N + n)*3 + 2];
        float a2 = x*x + y*y + z*z;
        float mn = INFINITY;
        #pragma unroll
        for (int s = 0; s < KSEG; ++s)
            mn = fminf(mn, part[(s*B + b)*N + n]);
        csum += a2 + mn;
    }

    // l2: sum of squared diffs over flattened objects
    float lsum = 0.f;
    for (int i = tid; i < OBJ_ELEMS; i += 256) {
        float d = adv_obj[b*OBJ_ELEMS + i] - ori_obj[b*OBJ_ELEMS + i];
        lsum += d * d;
    }

    // block reduce (4 waves of 64)
    #pragma unroll
    for (int off = 32; off; off >>= 1) {
        csum += __shfl_down(csum, off);
        lsum += __shfl_down(lsum, off);
    }
    __shared__ float scs[4], sls[4];
    int wave = tid >> 6, lane = tid & 63;
    if (lane == 0) { scs[wave] = csum; sls[wave] = lsum; }
    __syncthreads();
    if (tid == 0) {
        float c = scs[0] + scs[1] + scs[2] + scs[3];
        float l = sls[0] + sls[1] + sls[2] + sls[3];
        res[b]     = c / (float)N;          // loss1[b]
        res[B + b] = sqrtf(l + EPS_F);      // l2[b]
    }
}

__global__ __launch_bounds__(64) void final_combine_kernel(
    const float* __restrict__ res, const float* __restrict__ w,
    float* __restrict__ out)
{
    int t = threadIdx.x;                    // one wave
    float c = 0.f, l = 0.f;
    if (t < B) {
        c = res[t]     * w[t];
        l = res[B + t] * w[t];
    }
    #pragma unroll
    for (int off = 8; off; off >>= 1) {
        c += __shfl_down(c, off);
        l += __shfl_down(l, off);
    }
    if (t == 0) out[0] = l / (float)B + CD_W * (c / (float)B);
}

extern "C" void kernel_launch(void* const* d_in, const int* in_sizes, int n_in,
                              void* d_out, int out_size, void* d_ws, size_t ws_size,
                              hipStream_t stream)
{
    const float* adv_pc  = (const float*)d_in[0];
    const float* ori_pc  = (const float*)d_in[1];
    const float* adv_obj = (const float*)d_in[2];
    const float* ori_obj = (const float*)d_in[3];
    const float* weights = (const float*)d_in[4];
    float* out = (float*)d_out;
    float* ws  = (float*)d_ws;

    float* packed = ws;
    float* part   = ws + PART_OFF;
    float* res    = ws + RES_OFF;

    // 1) pack ori points with their squared norms
    pack_ori_kernel<<<dim3((B*K + 255) / 256), dim3(256), 0, stream>>>(ori_pc, packed);

    // 2) chamfer partial minima: grid = (1, KSEG, B)
    chamfer_part_kernel<<<dim3(1, KSEG, B), dim3(BLK1), 0, stream>>>(adv_pc, packed, part);

    // 3) per-batch reduction (chamfer mean + L2)
    batch_reduce_kernel<<<dim3(B), dim3(256), 0, stream>>>(adv_pc, part, adv_obj, ori_obj, res);

    // 4) combine with weights into the scalar output
    final_combine_kernel<<<dim3(1), dim3(64), 0, stream>>>(res, weights, out);
}

// Round 2
// 48.628 us; speedup vs baseline: 1.2817x; 1.2817x over previous
//
#include <hip/hip_runtime.h>
#include <math.h>

#define B 16
#define N 4096
#define K 4096
#define OBJ_ELEMS (8*512*3)   // 12288 per batch
#define KSEG 16
#define KS (K/KSEG)           // 256 ori points per segment
#define NSPLIT 4
#define NCHUNK (N/NSPLIT)     // 1024 adv points per block
#define BLK1 512
#define P (NCHUNK/BLK1)       // 2 adv points per thread
#define CD_W 0.2f
#define EPS_F 1e-7f

// ws layout (floats):
//   [0,           B*K*4)        packed ori {-2x,-2y,-2z,o2}
//   [PART_OFF,    +KSEG*B*N)    partial minima of (o2 - 2*dot)
//   [RES_OFF,     +2*B)         per-batch chamfer loss1 [B], l2 [B]
#define PACKED_SZ (B*K*4)
#define PART_OFF  PACKED_SZ
#define PART_SZ   (KSEG*B*N)
#define RES_OFF   (PART_OFF + PART_SZ)

__global__ __launch_bounds__(256) void pack_ori_kernel(
    const float* __restrict__ ori, float* __restrict__ packed)
{
    int i = blockIdx.x * 256 + threadIdx.x;   // point index in [0, B*K)
    if (i >= B * K) return;
    float x = ori[i*3 + 0];
    float y = ori[i*3 + 1];
    float z = ori[i*3 + 2];
    float4 v = make_float4(-2.f*x, -2.f*y, -2.f*z, x*x + y*y + z*z);
    reinterpret_cast<float4*>(packed)[i] = v;
}

__global__ __launch_bounds__(BLK1) void chamfer_part_kernel(
    const float* __restrict__ adv, const float* __restrict__ packed,
    float* __restrict__ part)
{
    __shared__ float4 lo[KS];
    const int nseg = blockIdx.x;
    const int kseg = blockIdx.y;
    const int b    = blockIdx.z;
    const int tid  = threadIdx.x;

    // stage this block's ori segment into LDS (packed {-2x,-2y,-2z,o2})
    if (tid < KS) {
        lo[tid] = reinterpret_cast<const float4*>(packed)[b*K + kseg*KS + tid];
    }

    // load this thread's P adv points into registers
    float ax[P], ay[P], az[P], m[P];
    #pragma unroll
    for (int p = 0; p < P; ++p) {
        int n = nseg*NCHUNK + tid + p * BLK1;
        ax[p] = adv[(b*N + n)*3 + 0];
        ay[p] = adv[(b*N + n)*3 + 1];
        az[p] = adv[(b*N + n)*3 + 2];
        m[p]  = INFINITY;
    }
    __syncthreads();

    #pragma unroll 8
    for (int k = 0; k < KS; ++k) {
        float4 o = lo[k];
        #pragma unroll
        for (int p = 0; p < P; ++p) {
            float t = __builtin_fmaf(ax[p], o.x, o.w);   // o2 - 2x*ax
            t = __builtin_fmaf(ay[p], o.y, t);
            t = __builtin_fmaf(az[p], o.z, t);
            m[p] = fminf(m[p], t);
        }
    }

    #pragma unroll
    for (int p = 0; p < P; ++p) {
        int n = nseg*NCHUNK + tid + p * BLK1;
        part[(kseg*B + b)*N + n] = m[p];
    }
}

__global__ __launch_bounds__(256) void batch_reduce_kernel(
    const float* __restrict__ adv, const float* __restrict__ part,
    const float* __restrict__ adv_obj, const float* __restrict__ ori_obj,
    float* __restrict__ res)
{
    const int b   = blockIdx.x;
    const int tid = threadIdx.x;

    // chamfer: sum over n of (a2[n] + min over segments)
    float csum = 0.f;
    for (int n = tid; n < N; n += 256) {
        float x = adv[(b*N + n)*3 + 0];
        float y = adv[(b*N + n)*3 + 1];
        float z = adv[(b*N + n)*3 + 2];
        float a2 = x*x + y*y + z*z;
        float mn = INFINITY;
        #pragma unroll
        for (int s = 0; s < KSEG; ++s)
            mn = fminf(mn, part[(s*B + b)*N + n]);
        csum += a2 + mn;
    }

    // l2: sum of squared diffs over flattened objects
    float lsum = 0.f;
    for (int i = tid; i < OBJ_ELEMS; i += 256) {
        float d = adv_obj[b*OBJ_ELEMS + i] - ori_obj[b*OBJ_ELEMS + i];
        lsum += d * d;
    }

    // block reduce (4 waves of 64)
    #pragma unroll
    for (int off = 32; off; off >>= 1) {
        csum += __shfl_down(csum, off);
        lsum += __shfl_down(lsum, off);
    }
    __shared__ float scs[4], sls[4];
    int wave = tid >> 6, lane = tid & 63;
    if (lane == 0) { scs[wave] = csum; sls[wave] = lsum; }
    __syncthreads();
    if (tid == 0) {
        float c = scs[0] + scs[1] + scs[2] + scs[3];
        float l = sls[0] + sls[1] + sls[2] + sls[3];
        res[b]     = c / (float)N;          // loss1[b]
        res[B + b] = sqrtf(l + EPS_F);      // l2[b]
    }
}

__global__ __launch_bounds__(64) void final_combine_kernel(
    const float* __restrict__ res, const float* __restrict__ w,
    float* __restrict__ out)
{
    int t = threadIdx.x;                    // one wave
    float c = 0.f, l = 0.f;
    if (t < B) {
        c = res[t]     * w[t];
        l = res[B + t] * w[t];
    }
    #pragma unroll
    for (int off = 8; off; off >>= 1) {
        c += __shfl_down(c, off);
        l += __shfl_down(l, off);
    }
    if (t == 0) out[0] = l / (float)B + CD_W * (c / (float)B);
}

extern "C" void kernel_launch(void* const* d_in, const int* in_sizes, int n_in,
                              void* d_out, int out_size, void* d_ws, size_t ws_size,
                              hipStream_t stream)
{
    const float* adv_pc  = (const float*)d_in[0];
    const float* ori_pc  = (const float*)d_in[1];
    const float* adv_obj = (const float*)d_in[2];
    const float* ori_obj = (const float*)d_in[3];
    const float* weights = (const float*)d_in[4];
    float* out = (float*)d_out;
    float* ws  = (float*)d_ws;

    float* packed = ws;
    float* part   = ws + PART_OFF;
    float* res    = ws + RES_OFF;

    // 1) pack ori points scaled by -2, with squared norms
    pack_ori_kernel<<<dim3((B*K + 255) / 256), dim3(256), 0, stream>>>(ori_pc, packed);

    // 2) chamfer partial minima: grid = (NSPLIT, KSEG, B) = 1024 blocks
    chamfer_part_kernel<<<dim3(NSPLIT, KSEG, B), dim3(BLK1), 0, stream>>>(adv_pc, packed, part);

    // 3) per-batch reduction (chamfer mean + L2)
    batch_reduce_kernel<<<dim3(B), dim3(256), 0, stream>>>(adv_pc, part, adv_obj, ori_obj, res);

    // 4) combine with weights into the scalar output
    final_combine_kernel<<<dim3(1), dim3(64), 0, stream>>>(res, weights, out);
}

// Round 3
// 36.768 us; speedup vs baseline: 1.6951x; 1.3226x over previous
//
#include <hip/hip_runtime.h>
#include <math.h>

#define B 16
#define N 4096
#define K 4096
#define OBJ_ELEMS (8*512*3)   // 12288 per batch
#define OBJ_VEC4  (OBJ_ELEMS/4) // 3072 float4 per batch
#define KSEG 16
#define KS (K/KSEG)           // 256 ori points per segment
#define NSPLIT 4
#define NCHUNK (N/NSPLIT)     // 1024 adv points per block
#define BLK1 256
#define P (NCHUNK/BLK1)       // 4 adv points per thread
#define M 16                  // n-splits in the reduce
#define NR (N/M)              // 256 points per reduce block
#define OBJ_V4_PER_BLK (OBJ_VEC4/M) // 192 float4 per reduce block
#define CD_W 0.2f
#define EPS_F 1e-7f

// ws layout (floats):
//   [0,            B*K*4)       packed ori {-2x,-2y,-2z,o2}
//   [PART_OFF,     +KSEG*B*N)   partial minima of (o2 - 2*dot)
//   [PC_OFF,       +B*M)        partial chamfer sums
//   [PL_OFF,       +B*M)        partial l2 sq-sums
#define PACKED_SZ (B*K*4)
#define PART_OFF  PACKED_SZ
#define PART_SZ   (KSEG*B*N)
#define PC_OFF    (PART_OFF + PART_SZ)
#define PL_OFF    (PC_OFF + B*M)

__global__ __launch_bounds__(256) void pack_ori_kernel(
    const float* __restrict__ ori, float* __restrict__ packed)
{
    int i = blockIdx.x * 256 + threadIdx.x;   // point index in [0, B*K)
    if (i >= B * K) return;
    float x = ori[i*3 + 0];
    float y = ori[i*3 + 1];
    float z = ori[i*3 + 2];
    float4 v = make_float4(-2.f*x, -2.f*y, -2.f*z, x*x + y*y + z*z);
    reinterpret_cast<float4*>(packed)[i] = v;
}

__global__ __launch_bounds__(BLK1) void chamfer_part_kernel(
    const float* __restrict__ adv, const float* __restrict__ packed,
    float* __restrict__ part)
{
    __shared__ float4 lo[KS];
    const int nseg = blockIdx.x;
    const int kseg = blockIdx.y;
    const int b    = blockIdx.z;
    const int tid  = threadIdx.x;

    // stage this block's ori segment into LDS (packed {-2x,-2y,-2z,o2})
    lo[tid] = reinterpret_cast<const float4*>(packed)[b*K + kseg*KS + tid];

    // load this thread's P adv points into registers
    float ax[P], ay[P], az[P], m[P];
    #pragma unroll
    for (int p = 0; p < P; ++p) {
        int n = nseg*NCHUNK + tid + p * BLK1;
        ax[p] = adv[(b*N + n)*3 + 0];
        ay[p] = adv[(b*N + n)*3 + 1];
        az[p] = adv[(b*N + n)*3 + 2];
        m[p]  = INFINITY;
    }
    __syncthreads();

    #pragma unroll 4
    for (int k = 0; k < KS; k += 2) {
        float4 o0 = lo[k];
        float4 o1 = lo[k+1];
        #pragma unroll
        for (int p = 0; p < P; ++p) {
            float t0 = __builtin_fmaf(ax[p], o0.x, o0.w);
            t0 = __builtin_fmaf(ay[p], o0.y, t0);
            t0 = __builtin_fmaf(az[p], o0.z, t0);
            float t1 = __builtin_fmaf(ax[p], o1.x, o1.w);
            t1 = __builtin_fmaf(ay[p], o1.y, t1);
            t1 = __builtin_fmaf(az[p], o1.z, t1);
            m[p] = fminf(fminf(t0, t1), m[p]);   // -> v_min3_f32
        }
    }

    #pragma unroll
    for (int p = 0; p < P; ++p) {
        int n = nseg*NCHUNK + tid + p * BLK1;
        part[(kseg*B + b)*N + n] = m[p];
    }
}

__global__ __launch_bounds__(256) void reduce_partial_kernel(
    const float* __restrict__ adv, const float* __restrict__ part,
    const float* __restrict__ adv_obj, const float* __restrict__ ori_obj,
    float* __restrict__ partC, float* __restrict__ partL)
{
    const int mblk = blockIdx.x;
    const int b    = blockIdx.y;
    const int tid  = threadIdx.x;

    // chamfer: one n per thread; a2[n] + min over 16 segments
    const int n = mblk * NR + tid;
    float x = adv[(b*N + n)*3 + 0];
    float y = adv[(b*N + n)*3 + 1];
    float z = adv[(b*N + n)*3 + 2];
    float a2 = x*x + y*y + z*z;
    float mn = INFINITY;
    #pragma unroll
    for (int s = 0; s < KSEG; ++s)
        mn = fminf(mn, part[(s*B + b)*N + n]);
    float csum = a2 + mn;

    // l2: vectorized squared-diff over this block's obj slice
    float lsum = 0.f;
    if (tid < OBJ_V4_PER_BLK) {
        int v4 = b*OBJ_VEC4 + mblk*OBJ_V4_PER_BLK + tid;
        float4 a = reinterpret_cast<const float4*>(adv_obj)[v4];
        float4 o = reinterpret_cast<const float4*>(ori_obj)[v4];
        float dx = a.x - o.x, dy = a.y - o.y, dz = a.z - o.z, dw = a.w - o.w;
        lsum = dx*dx + dy*dy + dz*dz + dw*dw;
    }

    // block reduce (4 waves of 64)
    #pragma unroll
    for (int off = 32; off; off >>= 1) {
        csum += __shfl_down(csum, off);
        lsum += __shfl_down(lsum, off);
    }
    __shared__ float scs[4], sls[4];
    int wave = tid >> 6, lane = tid & 63;
    if (lane == 0) { scs[wave] = csum; sls[wave] = lsum; }
    __syncthreads();
    if (tid == 0) {
        partC[b*M + mblk] = scs[0] + scs[1] + scs[2] + scs[3];
        partL[b*M + mblk] = sls[0] + sls[1] + sls[2] + sls[3];
    }
}

__global__ __launch_bounds__(256) void final_combine_kernel(
    const float* __restrict__ partC, const float* __restrict__ partL,
    const float* __restrict__ w, float* __restrict__ out)
{
    const int tid = threadIdx.x;          // 256 = B*M
    const int b   = tid >> 4;
    float c = partC[tid];
    float l = partL[tid];
    // reduce within 16-lane groups (one group per batch)
    #pragma unroll
    for (int off = 8; off; off >>= 1) {
        c += __shfl_down(c, off, 16);
        l += __shfl_down(l, off, 16);
    }
    __shared__ float sc[B], sl[B];
    if ((tid & 15) == 0) { sc[b] = c; sl[b] = l; }
    __syncthreads();
    if (tid < 64) {
        float cc = 0.f, ll = 0.f;
        if (tid < B) {
            float wt = w[tid];
            cc = (sc[tid] / (float)N) * wt;
            ll = sqrtf(sl[tid] + EPS_F) * wt;
        }
        #pragma unroll
        for (int off = 8; off; off >>= 1) {
            cc += __shfl_down(cc, off);
            ll += __shfl_down(ll, off);
        }
        if (tid == 0) out[0] = ll / (float)B + CD_W * (cc / (float)B);
    }
}

extern "C" void kernel_launch(void* const* d_in, const int* in_sizes, int n_in,
                              void* d_out, int out_size, void* d_ws, size_t ws_size,
                              hipStream_t stream)
{
    const float* adv_pc  = (const float*)d_in[0];
    const float* ori_pc  = (const float*)d_in[1];
    const float* adv_obj = (const float*)d_in[2];
    const float* ori_obj = (const float*)d_in[3];
    const float* weights = (const float*)d_in[4];
    float* out = (float*)d_out;
    float* ws  = (float*)d_ws;

    float* packed = ws;
    float* part   = ws + PART_OFF;
    float* partC  = ws + PC_OFF;
    float* partL  = ws + PL_OFF;

    // 1) pack ori points scaled by -2, with squared norms
    pack_ori_kernel<<<dim3((B*K + 255) / 256), dim3(256), 0, stream>>>(ori_pc, packed);

    // 2) chamfer partial minima: grid = (NSPLIT, KSEG, B) = 1024 blocks of 256
    chamfer_part_kernel<<<dim3(NSPLIT, KSEG, B), dim3(BLK1), 0, stream>>>(adv_pc, packed, part);

    // 3) parallel per-batch reduction partials: grid = (M, B) = 256 blocks
    reduce_partial_kernel<<<dim3(M, B), dim3(256), 0, stream>>>(
        adv_pc, part, adv_obj, ori_obj, partC, partL);

    // 4) combine partials with weights into the scalar output
    final_combine_kernel<<<dim3(1), dim3(256), 0, stream>>>(partC, partL, weights, out);
}